// Round 16
// baseline (588.834 us; speedup 1.0000x reference)
//
#include <hip/hip_runtime.h>
#include <math.h>

typedef __bf16 bf16;
typedef float f32x4 __attribute__((ext_vector_type(4)));
typedef bf16 bf16x8 __attribute__((ext_vector_type(8)));
typedef bf16 bf16x4 __attribute__((ext_vector_type(4)));
typedef bf16 bf16x2 __attribute__((ext_vector_type(2)));

// async global->LDS, 16B per lane; lds base must be wave-uniform
__device__ __forceinline__ void gll16(const void* g, void* l) {
    __builtin_amdgcn_global_load_lds(
        (const __attribute__((address_space(1))) void*)g,
        (__attribute__((address_space(3))) void*)l, 16, 0, 0);
}

// ---------------- fused fp32 -> bf16 convert (all weights, one dispatch) ----------------
struct CvtJobs {
    const float* s[8];
    bf16*        d[8];
    int          blk[10];   // cumulative block offsets; each block = 2048 elems
};

__global__ __launch_bounds__(256) void lam_cvt_all(CvtJobs J) {
    int b = blockIdx.x, j = 0;
    #pragma unroll
    for (int q = 1; q < 8; ++q) if (b >= J.blk[q]) j = q;
    const int i = (b - J.blk[j]) * 2048 + threadIdx.x * 8;
    const float* s = J.s[j];
    float4 a = *(const float4*)(s + i);
    float4 c = *(const float4*)(s + i + 4);
    bf16x8 o;
    o[0] = (bf16)a.x; o[1] = (bf16)a.y; o[2] = (bf16)a.z; o[3] = (bf16)a.w;
    o[4] = (bf16)c.x; o[5] = (bf16)c.y; o[6] = (bf16)c.z; o[7] = (bf16)c.w;
    *(bf16x8*)(J.d[j] + i) = o;
}

// ---------------- prep: packb (12 blocks) + bcomb/zb (256) + cb16 (4) ----------------
__global__ __launch_bounds__(256) void lam_prep(const float* __restrict__ bq,
                                                const float* __restrict__ bk,
                                                const float* __restrict__ bv,
                                                float* __restrict__ bqkv,
                                                const float* __restrict__ ca_wo,
                                                const float* __restrict__ ca_bv,
                                                const float* __restrict__ ca_bo,
                                                float* __restrict__ bcomb,
                                                float* __restrict__ zb,
                                                const bf16* __restrict__ Wout,
                                                const float* __restrict__ fb2,
                                                const float* __restrict__ ob,
                                                float* __restrict__ cb16) {
    const int b = blockIdx.x;
    const int tid = threadIdx.x;
    if (b < 12) {                                  // packb
        int i = b * 256 + tid;
        if (i < 1024) bqkv[i] = bq[i];
        else if (i < 2048) bqkv[i] = bk[i - 1024];
        else if (i < 3072) bqkv[i] = bv[i - 2048];
        return;
    }
    if (b < 268) {                                 // bcomb + zb
        const int bb = b - 12;
        const int lane = tid & 63;
        const int i = bb * 4 + (tid >> 6);
        float acc = 0.f;
        const float4* wp = (const float4*)(ca_wo + (long)i * 1024);
        const float4* bp = (const float4*)ca_bv;
        #pragma unroll
        for (int k = 0; k < 4; ++k) {
            const int q = lane + k * 64;
            float4 w = wp[q], v = bp[q];
            acc += w.x*v.x + w.y*v.y + w.z*v.z + w.w*v.w;
        }
        #pragma unroll
        for (int m = 32; m >= 1; m >>= 1) acc += __shfl_xor(acc, m);
        if (lane == 0) bcomb[i] = acc + ca_bo[i];
        const int gid = bb * 256 + tid;
        if (gid < 1024) zb[gid] = 0.f;
        return;
    }
    {                                              // cb16
        const int lane = tid & 63;
        const int j = (b - 268) * 4 + (tid >> 6);
        float acc = 0.f;
        #pragma unroll
        for (int m = 0; m < 16; ++m) {
            const int k = lane + m * 64;
            acc += (float)Wout[(long)j * 1024 + k] * fb2[k];
        }
        #pragma unroll
        for (int m = 32; m >= 1; m >>= 1) acc += __shfl_xor(acc, m);
        if (lane == 0) cb16[j] = acc + ob[j];
    }
}

// ---------------- transpose 1024x1024 fp32 -> bf16 (WvT[j][k] = wv[k][j]) ----------------
__global__ __launch_bounds__(256) void lam_transpose(const float* __restrict__ src,
                                                     bf16* __restrict__ dst) {
    __shared__ float tile[64][65];
    const int tid = threadIdx.x;
    const int bx = blockIdx.x * 64;
    const int by = blockIdx.y * 64;
    #pragma unroll
    for (int i = 0; i < 4; ++i) {
        const int r = (tid >> 4) + i * 16;
        const int c = (tid & 15) * 4;
        float4 v = *(const float4*)(src + (long)(by + r) * 1024 + bx + c);
        tile[r][c] = v.x; tile[r][c+1] = v.y; tile[r][c+2] = v.z; tile[r][c+3] = v.w;
    }
    __syncthreads();
    #pragma unroll
    for (int i = 0; i < 4; ++i) {
        const int r = (tid >> 4) + i * 16;
        const int c = (tid & 15) * 4;
        bf16x4 o;
        o[0] = (bf16)tile[c][r]; o[1] = (bf16)tile[c+1][r];
        o[2] = (bf16)tile[c+2][r]; o[3] = (bf16)tile[c+3][r];
        *(bf16x4*)(dst + (long)(bx + r) * 1024 + by + c) = o;
    }
}

// ---------------- Wof[j][c] = sum_d Wout[j][d]*ff_w2[d][c] (16x2048), parallel ----------------
__global__ __launch_bounds__(256) void lam_wof2(const bf16* __restrict__ Wout,
                                                const float* __restrict__ ff_w2,
                                                bf16* __restrict__ Wof) {
    __shared__ bf16 wo[16 * 1024];           // 32 KB
    __shared__ float red[16][16][16];        // [slice][c][j], 16 KB
    const int tid = threadIdx.x;
    for (int i = tid * 8; i < 16384; i += 2048)
        *(bf16x8*)(wo + i) = *(const bf16x8*)(Wout + i);
    __syncthreads();
    const int cl = tid & 15;                 // local column
    const int sl = tid >> 4;                 // K-slice 0..15
    const long c = (long)blockIdx.x * 16 + cl;
    float acc[16] = {};
    for (int dd = 0; dd < 64; ++dd) {
        const int d = sl * 64 + dd;
        const float x = ff_w2[(long)d * 2048 + c];
        #pragma unroll
        for (int j = 0; j < 16; ++j) acc[j] += x * (float)wo[j * 1024 + d];
    }
    #pragma unroll
    for (int j = 0; j < 16; ++j) red[sl][cl][j] = acc[j];
    __syncthreads();
    const int rj = tid & 15, rc = tid >> 4;  // rc 0..15
    float s = 0.f;
    #pragma unroll
    for (int sl2 = 0; sl2 < 16; ++sl2) s += red[sl2][rc][rj];
    Wof[(long)rj * 2048 + blockIdx.x * 16 + rc] = (bf16)s;
}

// ---------------- dot16m: MFMA skinny GEMM out[r][j] = X[r].Wo[j]  (K=1024) ----------------
__global__ __launch_bounds__(256) void lam_dot16m(const bf16* __restrict__ X,
                                                  const bf16* __restrict__ Wo,
                                                  float* __restrict__ out, int M) {
    __shared__ bf16 ws[16 * 1024];   // 32 KB, swizzled
    const int tid = threadIdx.x;
    for (int i = tid * 8; i < 16384; i += 2048) {
        const int col = i >> 10, k = i & 1023;
        *(bf16x8*)(ws + col * 1024 + (k ^ ((col & 7) << 3))) = *(const bf16x8*)(Wo + i);
    }
    __syncthreads();

    const int lane = tid & 63;
    const int wid  = tid >> 6;
    const long rbase = (long)blockIdx.x * 64 + wid * 16;
    if (rbase >= M) return;
    const int cidx = lane & 15;
    const int kg   = lane >> 4;

    const bf16* ar = X + (rbase + cidx) * 1024 + kg * 8;
    const int bbase = cidx * 1024;
    const int bxor  = (cidx & 7) << 3;

    f32x4 acc = {};
    #pragma unroll 4
    for (int kt = 0; kt < 32; ++kt) {
        bf16x8 a = *(const bf16x8*)(ar + kt * 32);
        bf16x8 b = *(const bf16x8*)(ws + bbase + ((kt * 32 + kg * 8) ^ bxor));
        acc = __builtin_amdgcn_mfma_f32_16x16x32_bf16(a, b, acc, 0, 0, 0);
    }
    #pragma unroll
    for (int q = 0; q < 4; ++q) {
        const long r = rbase + kg * 4 + q;
        if (r < M) out[r * 16 + cidx] = acc[q];
    }
}

// ---------------- LayerNorm helper (wave-wide, 16 vals/lane) ----------------
__device__ __forceinline__ void ln_row(float (&v)[16], const float* g, const float* bta,
                                       int lane, bf16* out) {
    float s = 0.f;
    #pragma unroll
    for (int e = 0; e < 16; ++e) s += v[e];
    #pragma unroll
    for (int m = 32; m >= 1; m >>= 1) s += __shfl_xor(s, m);
    const float mean = s * (1.0f / 1024.0f);
    float vs = 0.f;
    #pragma unroll
    for (int e = 0; e < 16; ++e) { float d = v[e] - mean; vs += d * d; }
    #pragma unroll
    for (int m = 32; m >= 1; m >>= 1) vs += __shfl_xor(vs, m);
    const float rstd = rsqrtf(vs * (1.0f / 1024.0f) + 1e-5f);
    const int kb = lane * 16;
    const float4* gp = (const float4*)(g + kb);
    const float4* bp = (const float4*)(bta + kb);
    float r[16];
    #pragma unroll
    for (int q = 0; q < 4; ++q) {
        float4 a = gp[q], c = bp[q];
        r[q*4+0] = (v[q*4+0] - mean) * rstd * a.x + c.x;
        r[q*4+1] = (v[q*4+1] - mean) * rstd * a.y + c.y;
        r[q*4+2] = (v[q*4+2] - mean) * rstd * a.z + c.z;
        r[q*4+3] = (v[q*4+3] - mean) * rstd * a.w + c.w;
    }
    bf16x8 o0, o1;
    #pragma unroll
    for (int e = 0; e < 8; ++e) { o0[e] = (bf16)r[e]; o1[e] = (bf16)r[8+e]; }
    bf16x8* yp = (bf16x8*)out;
    yp[0] = o0; yp[1] = o1;
}

// ---------------- LayerNorm: one wave per 1024-elem row (fp32 in) ----------------
__global__ __launch_bounds__(256) void lam_ln_f32(const float* __restrict__ X,
                                                  const float* __restrict__ g,
                                                  const float* __restrict__ bta,
                                                  bf16* __restrict__ Y) {
    const int lane = threadIdx.x & 63;
    const long row = (long)blockIdx.x * 4 + (threadIdx.x >> 6);
    const long base = row * 1024 + lane * 16;
    float v[16];
    const float4* p = (const float4*)(X + base);
    #pragma unroll
    for (int q = 0; q < 4; ++q) {
        float4 f = p[q];
        v[q*4+0]=f.x; v[q*4+1]=f.y; v[q*4+2]=f.z; v[q*4+3]=f.w;
    }
    ln_row(v, g, bta, lane, Y + base);
}

// ---------------- xtab/ltab/xt16: 68 distinct embedding rows + LN1 + Wout dots ----------------
__global__ __launch_bounds__(256) void lam_xtab(const float* __restrict__ tok,
                                                const float* __restrict__ pos,
                                                const float* __restrict__ g,
                                                const float* __restrict__ bta,
                                                const bf16* __restrict__ WoutB,
                                                float* __restrict__ xtab,
                                                bf16* __restrict__ ltab,
                                                float* __restrict__ xt16) {
    const int lane = threadIdx.x & 63;
    const int j = blockIdx.x * 4 + (threadIdx.x >> 6);
    if (j >= 68) return;
    const int t = j / 17, s = j % 17;
    float v[16];
    const float4* tp = (const float4*)(tok + (long)s * 1024 + lane * 16);
    const float4* pp = (const float4*)(pos + (long)t * 1024 + lane * 16);
    float4* xp = (float4*)(xtab + (long)j * 1024 + lane * 16);
    #pragma unroll
    for (int q = 0; q < 4; ++q) {
        float4 a = tp[q], c = pp[q];
        float4 o; o.x=a.x+c.x; o.y=a.y+c.y; o.z=a.z+c.z; o.w=a.w+c.w;
        xp[q] = o;
        v[q*4+0]=o.x; v[q*4+1]=o.y; v[q*4+2]=o.z; v[q*4+3]=o.w;
    }
    // xt16[j][jj] = x . Wout[jj]
    #pragma unroll
    for (int jj = 0; jj < 16; ++jj) {
        const bf16x8* wp = (const bf16x8*)(WoutB + (long)jj * 1024 + lane * 16);
        bf16x8 w0 = wp[0], w1 = wp[1];
        float d = 0.f;
        #pragma unroll
        for (int e = 0; e < 8; ++e) d += v[e]*(float)w0[e] + v[8+e]*(float)w1[e];
        #pragma unroll
        for (int m = 32; m >= 1; m >>= 1) d += __shfl_xor(d, m);
        if (lane == 0) xt16[j * 16 + jj] = d;
    }
    ln_row(v, g, bta, lane, ltab + (long)j * 1024 + lane * 16);
}

// ---------------- attention table: 4369 tuples x 8 heads, one wave each ----------------
__global__ __launch_bounds__(256) void lam_attn_tab(const bf16* __restrict__ qkvtab,
                                                    bf16* __restrict__ atab) {
    const int lane = threadIdx.x & 63;
    const int unit = blockIdx.x * 4 + (threadIdx.x >> 6);
    const int u = unit >> 3, h = unit & 7;
    int t, s1 = 0, s2 = 0, s3 = 0;
    if (u == 0) { t = 0; }
    else if (u < 17) { t = 1; s1 = u - 1; }
    else if (u < 273) { t = 2; int v = u - 17; s1 = v >> 4; s2 = v & 15; }
    else { t = 3; int v = u - 273; s1 = v >> 8; s2 = (v >> 4) & 15; s3 = v & 15; }
    const int qs = (t == 0) ? 16 : (t == 1 ? s1 : (t == 2 ? s2 : s3));
    const int qrow = t * 17 + qs;
    const int krow[4] = { 16, 17 + s1, 34 + s2, 51 + s3 };
    const int base = h * 128 + lane * 2;

    bf16x2 qu = *(const bf16x2*)(qkvtab + (long)qrow * 3072 + base);
    const float q0 = (float)qu[0], q1 = (float)qu[1];
    float sc[4], v0[4], v1[4];
    #pragma unroll
    for (int j = 0; j < 4; ++j) {
        if (j <= t) {
            const bf16* kp = qkvtab + (long)krow[j] * 3072 + 1024 + base;
            bf16x2 ku = *(const bf16x2*)(kp);
            bf16x2 vu = *(const bf16x2*)(kp + 1024);
            sc[j] = q0 * (float)ku[0] + q1 * (float)ku[1];
            v0[j] = (float)vu[0]; v1[j] = (float)vu[1];
        } else { sc[j] = 0.f; v0[j] = 0.f; v1[j] = 0.f; }
    }
    #pragma unroll
    for (int m = 1; m < 64; m <<= 1)
        #pragma unroll
        for (int j = 0; j < 4; ++j)
            sc[j] += __shfl_xor(sc[j], m);
    const float scale = 0.08838834764831845f;   // 1/sqrt(128)
    float mx = -1e30f;
    #pragma unroll
    for (int j = 0; j < 4; ++j) if (j <= t) mx = fmaxf(mx, sc[j] * scale);
    float sum = 0.f, a[4];
    #pragma unroll
    for (int j = 0; j < 4; ++j) if (j <= t) { a[j] = expf(sc[j] * scale - mx); sum += a[j]; }
    const float inv = 1.0f / sum;
    float o0 = 0.f, o1 = 0.f;
    #pragma unroll
    for (int j = 0; j < 4; ++j) if (j <= t) { o0 += a[j] * inv * v0[j]; o1 += a[j] * inv * v1[j]; }
    bf16x2 ov; ov[0] = (bf16)o0; ov[1] = (bf16)o1;
    *(bf16x2*)(atab + (long)u * 1024 + base) = ov;
}

// ---------------- gather + residual + LN3 (LN output only) ----------------
__global__ __launch_bounds__(256) void lam_gather_ln(const int* __restrict__ tg,
                                                     const float* __restrict__ xtab,
                                                     const bf16* __restrict__ aotab,
                                                     const bf16* __restrict__ caO,
                                                     const float* __restrict__ g,
                                                     const float* __restrict__ bta,
                                                     bf16* __restrict__ Y, long r0) {
    const int lane = threadIdx.x & 63;
    const long rl = (long)blockIdx.x * 4 + (threadIdx.x >> 6);
    const long r = r0 + rl;
    const long b = r >> 2;
    const int t = (int)(r & 3);
    const int tg0 = (t >= 1) ? tg[b*4] : 0;
    const int tg1 = (t >= 2) ? tg[b*4+1] : 0;
    const int tg2 = (t >= 3) ? tg[b*4+2] : 0;
    const int st = (t == 0) ? 16 : (t == 1 ? tg0 : (t == 2 ? tg1 : tg2));
    const long xrow = t * 17 + st;
    long idx;
    if (t == 0) idx = 0;
    else if (t == 1) idx = 1 + tg0;
    else if (t == 2) idx = 17 + tg0 * 16 + tg1;
    else idx = 273 + tg0 * 256 + tg1 * 16 + tg2;

    const int kb = lane * 16;
    float v[16];
    const float4* xp = (const float4*)(xtab + xrow * 1024 + kb);
    const bf16x8* ap = (const bf16x8*)(aotab + idx * 1024 + kb);
    const bf16x8* cp = (const bf16x8*)(caO + b * 1024 + kb);
    bf16x8 a0 = ap[0], a1 = ap[1], c0 = cp[0], c1 = cp[1];
    #pragma unroll
    for (int q = 0; q < 4; ++q) {
        float4 f = xp[q];
        v[q*4+0]=f.x; v[q*4+1]=f.y; v[q*4+2]=f.z; v[q*4+3]=f.w;
    }
    #pragma unroll
    for (int e = 0; e < 8; ++e) { v[e] += (float)a0[e] + (float)c0[e]; v[8+e] += (float)a1[e] + (float)c1[e]; }
    ln_row(v, g, bta, lane, Y + rl * 1024 + kb);
}

// ===================== GEMM epilogue (shared) =====================
template<int EPI, int IM>
__device__ __forceinline__ void gemm_epi(f32x4 (&acc)[IM][4], const float* bias,
                                         bf16* C, const bf16* R,
                                         long bm, long bn, int wrow, int wcol,
                                         int lane, int N) {
    const int lr = (lane >> 4) * 4;
    const int lc = lane & 15;
    #pragma unroll
    for (int i = 0; i < IM; ++i) {
        const long row0 = bm + wrow + i * 16 + lr;
        #pragma unroll
        for (int j = 0; j < 4; ++j) {
            const long col = bn + wcol + j * 16 + lc;
            const float bvs = bias[col];
            #pragma unroll
            for (int qq = 0; qq < 4; ++qq) {
                const long row = row0 + qq;
                float v = acc[i][j][qq] + bvs;
                const long idx = row * N + col;
                if (EPI == 1) v = 0.5f * v * (1.0f + erff(v * 0.70710678118654752f));
                if (EPI == 2) v = fmaxf(v, 0.0f);
                if (EPI == 3) v += (float)R[idx];
                C[idx] = (bf16)v;
            }
        }
    }
}

// ---------------- GEMM 2-phase (round-3/7 proven): TMx256, BK=64, 8 waves ----------------
// EPI 4 (TM=256 only): EPI0 epilogue + stage-2 contraction of the C tile with
// W16 (16 x N) slice at bn -> atomicAdd into out16 (gemm_fl's verified pattern).
template<int EPI, int TM>
__global__ __launch_bounds__(512, 2) void lam_gemm2(const bf16* __restrict__ A,
                                                    const bf16* __restrict__ W,
                                                    const float* __restrict__ bias,
                                                    bf16* C, const bf16* R,
                                                    const bf16* __restrict__ W16,
                                                    float* __restrict__ out16,
                                                    int M, int N, int K) {
    constexpr int AR    = TM / 64;
    constexpr int ABYTE = TM * 128;
    constexpr int BUFB  = ABYTE + 32768;
    constexpr int IM    = TM / 32;
    __shared__ __attribute__((aligned(16))) char lds[2 * BUFB];

    const int t    = threadIdx.x;
    const int lane = t & 63;
    const int wid  = t >> 6;
    const int wm   = wid >> 2;
    const int wn   = wid & 3;

    const int gx   = gridDim.x;
    const int nwg  = gx * gridDim.y;
    const int orig = blockIdx.y * gx + blockIdx.x;
    const int q8 = nwg >> 3, r8 = nwg & 7;
    const int xcd = orig & 7, i8 = orig >> 3;
    const int wg  = (xcd < r8 ? xcd * (q8 + 1) : r8 * (q8 + 1) + (xcd - r8) * q8) + i8;
    const long bm = (long)(wg / gx) * TM;
    const long bn = (long)(wg % gx) * 256;

    const long rs = (long)K * 2;
    const char* Ag = (const char*)A + bm * rs;
    const char* Wg = (const char*)W + bn * rs;
    const int  srow = t >> 3;
    const int  scol = (((t & 7) ^ ((t >> 3) & 7)) << 4);
    const long g0   = (long)srow * rs + scol;

    const int xorq = (lane & 7) << 4;
    const int arow = wm * (TM / 2) + (lane & 15);
    const int brow = wn * 64 + (lane & 15);
    const int kq   = (lane >> 4) * 16;

    f32x4 acc[IM][4] = {};

    auto STAGE = [&](int buf, long kbyte) {
        char* base = lds + buf * BUFB + wid * 1024;
        const char* ga = Ag + g0 + kbyte;
        const char* gb = Wg + g0 + kbyte;
        #pragma unroll
        for (int r = 0; r < AR; ++r)
            gll16(ga + (long)r * 64 * rs, base + r * 8192);
        #pragma unroll
        for (int r = 0; r < 4; ++r)
            gll16(gb + (long)r * 64 * rs, base + ABYTE + r * 8192);
    };

    STAGE(0, 0);
    asm volatile("s_waitcnt vmcnt(0)" ::: "memory");
    __syncthreads();

    const int NT = K >> 6;
    int cur = 0;
    for (int kt = 0; kt < NT; ++kt) {
        if (kt + 1 < NT) STAGE(cur ^ 1, (long)(kt + 1) * 128);
        const char* ab = lds + cur * BUFB;
        const char* bb = ab + ABYTE;
        #pragma unroll
        for (int ks = 0; ks < 2; ++ks) {
            const int kc = kq + ks * 64;
            bf16x8 bvv[4];
            #pragma unroll
            for (int j = 0; j < 4; ++j) {
                const int x = (brow + j * 16) * 128 + kc;
                bvv[j] = *(const bf16x8*)(bb + (x ^ xorq));
            }
            #pragma unroll
            for (int i = 0; i < IM; ++i) {
                const int x = (arow + i * 16) * 128 + kc;
                bf16x8 avv = *(const bf16x8*)(ab + (x ^ xorq));
                #pragma unroll
                for (int j = 0; j < 4; ++j)
                    acc[i][j] = __builtin_amdgcn_mfma_f32_16x16x32_bf16(avv, bvv[j], acc[i][j], 0, 0, 0);
            }
        }
        asm volatile("s_waitcnt vmcnt(0)" ::: "memory");
        __syncthreads();
        cur ^= 1;
    }

    if (EPI != 4) {
        gemm_epi<EPI, IM>(acc, bias, C, R, bm, bn, wm * (TM / 2), wn * 64, lane, N);
    } else {
        // ---- epilogue: write C tile + swizzled LDS copy (bf16-rounded once) ----
        const int lr = (lane >> 4) * 4;
        const int lc = lane & 15;
        #pragma unroll
        for (int i = 0; i < IM; ++i) {
            const int row0 = wm * (TM / 2) + i * 16 + lr;
            #pragma unroll
            for (int j = 0; j < 4; ++j) {
                const int col = wn * 64 + j * 16 + lc;
                const float bvs = bias[bn + col];
                #pragma unroll
                for (int qq = 0; qq < 4; ++qq) {
                    const int row = row0 + qq;
                    const bf16 v = (bf16)(acc[i][j][qq] + bvs);
                    C[(bm + row) * N + bn + col] = v;
                    *(bf16*)(lds + row * 512 + ((col * 2) ^ ((row & 7) << 4))) = v;
                }
            }
        }
        __syncthreads();
        // ---- stage 2: tile[256][256] @ W16 slice (16 x 256 at bn) ----
        const int cidx = lane & 15;
        const int kg   = lane >> 4;
        f32x4 acc2[2] = {};
        #pragma unroll
        for (int kt = 0; kt < 8; ++kt) {
            bf16x8 bfrag = *(const bf16x8*)(W16 + (long)cidx * 1024 + bn + kt * 32 + kg * 8);
            #pragma unroll
            for (int rt = 0; rt < 2; ++rt) {
                const int row = wid * 32 + rt * 16 + cidx;
                const int kby = (kt * 32 + kg * 8) * 2;
                bf16x8 afrag = *(const bf16x8*)(lds + row * 512 + (kby ^ ((row & 7) << 4)));
                acc2[rt] = __builtin_amdgcn_mfma_f32_16x16x32_bf16(afrag, bfrag, acc2[rt], 0, 0, 0);
            }
        }
        #pragma unroll
        for (int rt = 0; rt < 2; ++rt)
            #pragma unroll
            for (int q = 0; q < 4; ++q) {
                const long row = bm + wid * 32 + rt * 16 + kg * 4 + q;
                atomicAdd(&out16[row * 16 + cidx], acc2[rt][q]);
            }
    }
}

static void gemm2(int epi, const bf16* A, const bf16* W, const float* bias, bf16* C,
                  const bf16* R, int M, int N, int K, hipStream_t s) {
    const long n256 = (long)(M >> 8) * (N >> 8);
    if (n256 >= 256 && (M & 255) == 0) {
        dim3 grid(N / 256, M / 256);
        switch (epi) {
            case 0: lam_gemm2<0,256><<<grid,512,0,s>>>(A,W,bias,C,R,nullptr,nullptr,M,N,K); break;
            case 1: lam_gemm2<1,256><<<grid,512,0,s>>>(A,W,bias,C,R,nullptr,nullptr,M,N,K); break;
            case 2: lam_gemm2<2,256><<<grid,512,0,s>>>(A,W,bias,C,R,nullptr,nullptr,M,N,K); break;
            default:lam_gemm2<3,256><<<grid,512,0,s>>>(A,W,bias,C,R,nullptr,nullptr,M,N,K); break;
        }
    } else {
        dim3 grid(N / 256, M / 128);
        switch (epi) {
            case 0: lam_gemm2<0,128><<<grid,512,0,s>>>(A,W,bias,C,R,nullptr,nullptr,M,N,K); break;
            case 1: lam_gemm2<1,128><<<grid,512,0,s>>>(A,W,bias,C,R,nullptr,nullptr,M,N,K); break;
            case 2: lam_gemm2<2,128><<<grid,512,0,s>>>(A,W,bias,C,R,nullptr,nullptr,M,N,K); break;
            default:lam_gemm2<3,128><<<grid,512,0,s>>>(A,W,bias,C,R,nullptr,nullptr,M,N,K); break;
        }
    }
}

// ---------------- fused FFN1 + logits: 256x256 tile, then contract with Wof ----------------
__global__ __launch_bounds__(512, 2) void lam_gemm_fl(const bf16* __restrict__ A,
                                                      const bf16* __restrict__ W,
                                                      const float* __restrict__ bias,
                                                      const bf16* __restrict__ Wof,
                                                      const int* __restrict__ tg,
                                                      const float* __restrict__ xt16,
                                                      const float* __restrict__ ao16,
                                                      const float* __restrict__ ca16,
                                                      const float* __restrict__ cb16,
                                                      float* __restrict__ out,
                                                      long r0, int K) {
    constexpr int ABYTE = 32768;            // A region: 256 rows x 64 k x 2B
    constexpr int BUFB  = 65536;
    __shared__ __attribute__((aligned(16))) char lds[2 * BUFB];

    const int t    = threadIdx.x;
    const int lane = t & 63;
    const int wid  = t >> 6;
    const int wm   = wid >> 2;
    const int wn   = wid & 3;

    const int gx   = gridDim.x;             // 8 (N/256)
    const int nwg  = gx * gridDim.y;
    const int orig = blockIdx.y * gx + blockIdx.x;
    const int q8 = nwg >> 3, r8 = nwg & 7;
    const int xcd = orig & 7, i8 = orig >> 3;
    const int wg  = (xcd < r8 ? xcd * (q8 + 1) : r8 * (q8 + 1) + (xcd - r8) * q8) + i8;
    const long bm = (long)(wg / gx) * 256;  // chunk-local row base
    const long bn = (long)(wg % gx) * 256;  // FFN column base

    const long rs = (long)K * 2;
    const char* Ag = (const char*)A + bm * rs;
    const char* Wg = (const char*)W + bn * rs;
    const int  srow = t >> 3;
    const int  scol = (((t & 7) ^ ((t >> 3) & 7)) << 4);
    const long g0   = (long)srow * rs + scol;

    const int xorq = (lane & 7) << 4;
    const int arow = wm * 128 + (lane & 15);
    const int brow = wn * 64 + (lane & 15);
    const int kq   = (lane >> 4) * 16;

    f32x4 acc[8][4] = {};

    auto STAGE = [&](int buf, long kbyte) {
        char* base = lds + buf * BUFB + wid * 1024;
        const char* ga = Ag + g0 + kbyte;
        const char* gb = Wg + g0 + kbyte;
        #pragma unroll
        for (int r = 0; r < 4; ++r)
            gll16(ga + (long)r * 64 * rs, base + r * 8192);
        #pragma unroll
        for (int r = 0; r < 4; ++r)
            gll16(gb + (long)r * 64 * rs, base + ABYTE + r * 8192);
    };

    STAGE(0, 0);
    asm volatile("s_waitcnt vmcnt(0)" ::: "memory");
    __syncthreads();

    const int NT = K >> 6;
    int cur = 0;
    for (int kt = 0; kt < NT; ++kt) {
        if (kt + 1 < NT) STAGE(cur ^ 1, (long)(kt + 1) * 128);
        const char* ab = lds + cur * BUFB;
        const char* bb = ab + ABYTE;
        #pragma unroll
        for (int ks = 0; ks < 2; ++ks) {
            const int kc = kq + ks * 64;
            bf16x8 bvv[4];
            #pragma unroll
            for (int j = 0; j < 4; ++j) {
                const int x = (brow + j * 16) * 128 + kc;
                bvv[j] = *(const bf16x8*)(bb + (x ^ xorq));
            }
            #pragma unroll
            for (int i = 0; i < 8; ++i) {
                const int x = (arow + i * 16) * 128 + kc;
                bf16x8 avv = *(const bf16x8*)(ab + (x ^ xorq));
                #pragma unroll
                for (int j = 0; j < 4; ++j)
                    acc[i][j] = __builtin_amdgcn_mfma_f32_16x16x32_bf16(avv, bvv[j], acc[i][j], 0, 0, 0);
            }
        }
        asm volatile("s_waitcnt vmcnt(0)" ::: "memory");
        __syncthreads();
        cur ^= 1;
    }

    // ---- write relu tile [256 rows][256 cols] bf16 into LDS, swizzled ----
    {
        const int lr = (lane >> 4) * 4;
        const int lc = lane & 15;
        #pragma unroll
        for (int i = 0; i < 8; ++i) {
            const int row0 = wm * 128 + i * 16 + lr;
            #pragma unroll
            for (int j = 0; j < 4; ++j) {
                const int col = wn * 64 + j * 16 + lc;
                const float bvs = bias[bn + col];
                #pragma unroll
                for (int qq = 0; qq < 4; ++qq) {
                    const int row = row0 + qq;
                    const float v = fmaxf(acc[i][j][qq] + bvs, 0.0f);
                    *(bf16*)(lds + row * 512 + ((col * 2) ^ ((row & 7) << 4))) = (bf16)v;
                }
            }
        }
    }
    __syncthreads();

    // ---- 2nd stage: out_partial[256][16] = tile @ WofT(slice bn..bn+255) ----
    const int cidx = lane & 15;
    const int kg   = lane >> 4;
    f32x4 acc2[2] = {};
    #pragma unroll
    for (int kt = 0; kt < 8; ++kt) {
        bf16x8 bfrag = *(const bf16x8*)(Wof + (long)cidx * 2048 + bn + kt * 32 + kg * 8);
        #pragma unroll
        for (int rt = 0; rt < 2; ++rt) {
            const int row = wid * 32 + rt * 16 + cidx;
            const int kby = (kt * 32 + kg * 8) * 2;
            bf16x8 afrag = *(const bf16x8*)(lds + row * 512 + (kby ^ ((row & 7) << 4)));
            acc2[rt] = __builtin_amdgcn_mfma_f32_16x16x32_bf16(afrag, bfrag, acc2[rt], 0, 0, 0);
        }
    }

    // ---- atomic accumulate (bn==0 block also adds tables) ----
    #pragma unroll
    for (int rt = 0; rt < 2; ++rt) {
        #pragma unroll
        for (int q = 0; q < 4; ++q) {
            const long rl = bm + wid * 32 + rt * 16 + kg * 4 + q;
            const long r = r0 + rl;
            float v = acc2[rt][q];
            if (bn == 0) {
                const long b = r >> 2;
                const int tt = (int)(r & 3);
                const int tg0 = (tt >= 1) ? tg[b*4] : 0;
                const int tg1 = (tt >= 2) ? tg[b*4+1] : 0;
                const int tg2 = (tt >= 3) ? tg[b*4+2] : 0;
                const int st = (tt == 0) ? 16 : (tt == 1 ? tg0 : (tt == 2 ? tg1 : tg2));
                const long xrow = tt * 17 + st;
                long idx;
                if (tt == 0) idx = 0;
                else if (tt == 1) idx = 1 + tg0;
                else if (tt == 2) idx = 17 + tg0 * 16 + tg1;
                else idx = 273 + tg0 * 256 + tg1 * 16 + tg2;
                v += xt16[xrow * 16 + cidx] + ao16[idx * 16 + cidx]
                   + ca16[b * 16 + cidx] + cb16[cidx];
            }
            atomicAdd(&out[r * 16 + cidx], v);
        }
    }
}

// =============================== host ===============================
extern "C" void kernel_launch(void* const* d_in, const int* in_sizes, int n_in,
                              void* d_out, int out_size, void* d_ws, size_t ws_size,
                              hipStream_t stream) {
    const float* context = (const float*)d_in[0];
    const int*   targets = (const int*)d_in[1];
    const float* tok_emb = (const float*)d_in[2];
    const float* pos_emb = (const float*)d_in[3];
    const float* cp_ln_g = (const float*)d_in[4];
    const float* cp_ln_b = (const float*)d_in[5];
    const float* cp_w    = (const float*)d_in[6];
    const float* cp_b    = (const float*)d_in[7];
    const float* sa_wq   = (const float*)d_in[8];
    const float* sa_bq   = (const float*)d_in[9];
    const float* sa_wk   = (const float*)d_in[10];
    const float* sa_bk   = (const float*)d_in[11];
    const float* sa_wv   = (const float*)d_in[12];
    const float* sa_bv   = (const float*)d_in[13];
    const float* sa_wo   = (const float*)d_in[14];
    const float* sa_bo   = (const float*)d_in[15];
    // ca_wq/bq (16,17), ca_wk/bk (18,19), ln2 (26,27): dead — kv len is 1
    const float* ca_wv   = (const float*)d_in[20];
    const float* ca_bv   = (const float*)d_in[21];
    const float* ca_wo   = (const float*)d_in[22];
    const float* ca_bo   = (const float*)d_in[23];
    const float* ln1_g   = (const float*)d_in[24];
    const float* ln1_b   = (const float*)d_in[25];
    const float* ln3_g   = (const float*)d_in[28];
    const float* ln3_b   = (const float*)d_in[29];
    const float* ff_w1   = (const float*)d_in[30];
    const float* ff_b1   = (const float*)d_in[31];
    const float* ff_w2   = (const float*)d_in[32];
    const float* ff_b2   = (const float*)d_in[33];
    const float* out_w   = (const float*)d_in[34];
    const float* out_b   = (const float*)d_in[35];

    char* ws = (char*)d_ws;
    size_t off = 0;
    auto take = [&](size_t bytes) -> char* {
        char* p = ws + off;
        off += (bytes + 255) & ~(size_t)255;
        return p;
    };
    // ---- persistent: bf16 weights + tables + caO + context scratch ----
    bf16*  Wcp   = (bf16*)take((size_t)1048576 * 2);
    bf16*  Wqkv  = (bf16*)take((size_t)3145728 * 2);
    bf16*  Wsao  = (bf16*)take((size_t)1048576 * 2);
    bf16*  Wcao  = (bf16*)take((size_t)1048576 * 2);
    bf16*  WvT   = (bf16*)take((size_t)1048576 * 2);
    bf16*  Wcomb = (bf16*)take((size_t)1048576 * 2);
    bf16*  Wff1  = (bf16*)take((size_t)2097152 * 2);
    bf16*  Wout  = (bf16*)take((size_t)16384 * 2);
    bf16*  Wof   = (bf16*)take((size_t)32768 * 2);
    float* bqkv  = (float*)take((size_t)3072 * 4);
    float* bcomb = (float*)take((size_t)1024 * 4);
    float* zb    = (float*)take((size_t)1024 * 4);
    float* cb16  = (float*)take((size_t)16 * 4);
    float* xtab  = (float*)take((size_t)128 * 1024 * 4);
    bf16*  ltab  = (bf16*)take((size_t)128 * 1024 * 2);
    bf16*  qkvtab= (bf16*)take((size_t)128 * 3072 * 2);
    bf16*  atab  = (bf16*)take((size_t)4608 * 1024 * 2);
    bf16*  aotab = (bf16*)take((size_t)4608 * 1024 * 2);
    bf16*  caO   = (bf16*)take((size_t)16384 * 1024 * 2);
    float* xt16  = (float*)take((size_t)128 * 16 * 4);
    float* ao16  = (float*)take((size_t)4608 * 16 * 4);
    float* ca16  = (float*)take((size_t)16384 * 16 * 4);
    bf16*  cbuf  = (bf16*)take((size_t)16384 * 1024 * 2);   // context scratch

    // ---- adaptive chunk pool: hb (rows*1024 bf16) only ----
    long chunk_rows = 65536;
    while (chunk_rows > 512 &&
           off + (size_t)chunk_rows * 2048 > ws_size)
        chunk_rows >>= 1;
    bf16* hb = (bf16*)take((size_t)chunk_rows * 1024 * 2);
    const long nchunks = 65536 / chunk_rows;

    // --- zero accumulators up front (independent of everything) ---
    hipMemsetAsync(d_out, 0, (size_t)65536 * 16 * 4, stream);
    hipMemsetAsync(ca16, 0, (size_t)16384 * 16 * 4, stream);

    // --- all weight fp32->bf16 conversions in ONE dispatch (ff_w2 stays fp32) ---
    {
        CvtJobs J;
        const float* srcs[8] = { cp_w, sa_wq, sa_wk, sa_wv, sa_wo, ca_wo, ff_w1, out_w };
        bf16* dsts[8] = { Wcp, Wqkv, Wqkv + 1048576, Wqkv + 2097152, Wsao, Wcao, Wff1, Wout };
        const int ns[8] = { 1048576, 1048576, 1048576, 1048576, 1048576, 1048576,
                            2097152, 16384 };
        int cum = 0;
        for (int j = 0; j < 8; ++j) {
            J.s[j] = srcs[j]; J.d[j] = dsts[j];
            J.blk[j] = cum; cum += ns[j] / 2048;
        }
        J.blk[8] = cum; J.blk[9] = cum;
        lam_cvt_all<<<cum, 256, 0, stream>>>(J);
    }
    // --- prep: packb + bcomb/zb + cb16 in ONE dispatch ---
    lam_prep<<<272, 256, 0, stream>>>(sa_bq, sa_bk, sa_bv, bqkv,
                                      ca_wo, ca_bv, ca_bo, bcomb, zb,
                                      Wout, ff_b2, out_b, cb16);

    // --- folds: Wcomb = ca_wo@ca_wv; Wof = Wout@ff_w2 ---
    lam_transpose<<<dim3(16, 16), 256, 0, stream>>>(ca_wv, WvT);
    gemm2(0, Wcao, WvT, zb, Wcomb, nullptr, 1024, 1024, 1024, stream);
    lam_wof2<<<128, 256, 0, stream>>>(Wout, ff_w2, Wof);

    // --- decoder tables: x/LN1/xt16 (68), QKV (68), attention (4369), O-proj, ao16 ---
    lam_xtab<<<17, 256, 0, stream>>>(tok_emb, pos_emb, ln1_g, ln1_b, Wout, xtab, ltab, xt16);
    gemm2(0, ltab, Wqkv, bqkv, qkvtab, nullptr, 128, 3072, 1024, stream);
    lam_attn_tab<<<8738, 256, 0, stream>>>(qkvtab, atab);
    gemm2(0, atab, Wsao, sa_bo, aotab, nullptr, 4608, 1024, 1024, stream);
    lam_dot16m<<<72, 256, 0, stream>>>(aotab, Wout, ao16, 4608);

    // --- context path: LN -> gelu-GEMM -> GEMM(+fused ca16 contraction, EPI4) ---
    lam_ln_f32<<<4096, 256, 0, stream>>>(context, cp_ln_g, cp_ln_b, caO);
    gemm2(1, caO, Wcp, cp_b, cbuf, nullptr, 16384, 1024, 1024, stream);
    {
        dim3 grid(1024 / 256, 16384 / 256);
        lam_gemm2<4,256><<<grid, 512, 0, stream>>>(cbuf, Wcomb, bcomb, caO, nullptr,
                                                   Wout, ca16, 16384, 1024, 1024);
    }

    // --- decoder stream: per chunk: gather+LN3 -> fused FFN1+logits ---
    for (long c = 0; c < nchunks; ++c) {
        const long r0 = c * chunk_rows;
        lam_gather_ln<<<chunk_rows / 4, 256, 0, stream>>>(targets, xtab, aotab, caO,
                                                          ln3_g, ln3_b, hb, r0);
        lam_gemm_fl<<<dim3(8, chunk_rows / 256), 512, 0, stream>>>(
            hb, Wff1, ff_b1, Wof, targets, xt16, ao16, ca16, cb16,
            (float*)d_out, r0, 1024);
    }

    (void)in_sizes; (void)n_in; (void)out_size;
}

// Round 17
// 579.985 us; speedup vs baseline: 1.0153x; 1.0153x over previous
//
#include <hip/hip_runtime.h>
#include <math.h>

typedef __bf16 bf16;
typedef float f32x4 __attribute__((ext_vector_type(4)));
typedef bf16 bf16x8 __attribute__((ext_vector_type(8)));
typedef bf16 bf16x4 __attribute__((ext_vector_type(4)));
typedef bf16 bf16x2 __attribute__((ext_vector_type(2)));

// async global->LDS, 16B per lane; lds base must be wave-uniform
__device__ __forceinline__ void gll16(const void* g, void* l) {
    __builtin_amdgcn_global_load_lds(
        (const __attribute__((address_space(1))) void*)g,
        (__attribute__((address_space(3))) void*)l, 16, 0, 0);
}

// ---------------- fused fp32 -> bf16 convert (all weights, one dispatch) ----------------
struct CvtJobs {
    const float* s[8];
    bf16*        d[8];
    int          blk[10];   // cumulative block offsets; each block = 2048 elems
};

__global__ __launch_bounds__(256) void lam_cvt_all(CvtJobs J) {
    int b = blockIdx.x, j = 0;
    #pragma unroll
    for (int q = 1; q < 8; ++q) if (b >= J.blk[q]) j = q;
    const int i = (b - J.blk[j]) * 2048 + threadIdx.x * 8;
    const float* s = J.s[j];
    float4 a = *(const float4*)(s + i);
    float4 c = *(const float4*)(s + i + 4);
    bf16x8 o;
    o[0] = (bf16)a.x; o[1] = (bf16)a.y; o[2] = (bf16)a.z; o[3] = (bf16)a.w;
    o[4] = (bf16)c.x; o[5] = (bf16)c.y; o[6] = (bf16)c.z; o[7] = (bf16)c.w;
    *(bf16x8*)(J.d[j] + i) = o;
}

// ---------------- prep: packb (12 blocks) + bcomb/zb (256) + cb16 (4) ----------------
__global__ __launch_bounds__(256) void lam_prep(const float* __restrict__ bq,
                                                const float* __restrict__ bk,
                                                const float* __restrict__ bv,
                                                float* __restrict__ bqkv,
                                                const float* __restrict__ ca_wo,
                                                const float* __restrict__ ca_bv,
                                                const float* __restrict__ ca_bo,
                                                float* __restrict__ bcomb,
                                                float* __restrict__ zb,
                                                const bf16* __restrict__ Wout,
                                                const float* __restrict__ fb2,
                                                const float* __restrict__ ob,
                                                float* __restrict__ cb16) {
    const int b = blockIdx.x;
    const int tid = threadIdx.x;
    if (b < 12) {                                  // packb
        int i = b * 256 + tid;
        if (i < 1024) bqkv[i] = bq[i];
        else if (i < 2048) bqkv[i] = bk[i - 1024];
        else if (i < 3072) bqkv[i] = bv[i - 2048];
        return;
    }
    if (b < 268) {                                 // bcomb + zb
        const int bb = b - 12;
        const int lane = tid & 63;
        const int i = bb * 4 + (tid >> 6);
        float acc = 0.f;
        const float4* wp = (const float4*)(ca_wo + (long)i * 1024);
        const float4* bp = (const float4*)ca_bv;
        #pragma unroll
        for (int k = 0; k < 4; ++k) {
            const int q = lane + k * 64;
            float4 w = wp[q], v = bp[q];
            acc += w.x*v.x + w.y*v.y + w.z*v.z + w.w*v.w;
        }
        #pragma unroll
        for (int m = 32; m >= 1; m >>= 1) acc += __shfl_xor(acc, m);
        if (lane == 0) bcomb[i] = acc + ca_bo[i];
        const int gid = bb * 256 + tid;
        if (gid < 1024) zb[gid] = 0.f;
        return;
    }
    {                                              // cb16
        const int lane = tid & 63;
        const int j = (b - 268) * 4 + (tid >> 6);
        float acc = 0.f;
        #pragma unroll
        for (int m = 0; m < 16; ++m) {
            const int k = lane + m * 64;
            acc += (float)Wout[(long)j * 1024 + k] * fb2[k];
        }
        #pragma unroll
        for (int m = 32; m >= 1; m >>= 1) acc += __shfl_xor(acc, m);
        if (lane == 0) cb16[j] = acc + ob[j];
    }
}

// ---------------- transpose 1024x1024 fp32 -> bf16 (WvT[j][k] = wv[k][j]) ----------------
__global__ __launch_bounds__(256) void lam_transpose(const float* __restrict__ src,
                                                     bf16* __restrict__ dst) {
    __shared__ float tile[64][65];
    const int tid = threadIdx.x;
    const int bx = blockIdx.x * 64;
    const int by = blockIdx.y * 64;
    #pragma unroll
    for (int i = 0; i < 4; ++i) {
        const int r = (tid >> 4) + i * 16;
        const int c = (tid & 15) * 4;
        float4 v = *(const float4*)(src + (long)(by + r) * 1024 + bx + c);
        tile[r][c] = v.x; tile[r][c+1] = v.y; tile[r][c+2] = v.z; tile[r][c+3] = v.w;
    }
    __syncthreads();
    #pragma unroll
    for (int i = 0; i < 4; ++i) {
        const int r = (tid >> 4) + i * 16;
        const int c = (tid & 15) * 4;
        bf16x4 o;
        o[0] = (bf16)tile[c][r]; o[1] = (bf16)tile[c+1][r];
        o[2] = (bf16)tile[c+2][r]; o[3] = (bf16)tile[c+3][r];
        *(bf16x4*)(dst + (long)(bx + r) * 1024 + by + c) = o;
    }
}

// ---------------- Wof[j][c] = sum_d Wout[j][d]*ff_w2[d][c] (16x2048), parallel ----------------
__global__ __launch_bounds__(256) void lam_wof2(const bf16* __restrict__ Wout,
                                                const float* __restrict__ ff_w2,
                                                bf16* __restrict__ Wof) {
    __shared__ bf16 wo[16 * 1024];           // 32 KB
    __shared__ float red[16][16][16];        // [slice][c][j], 16 KB
    const int tid = threadIdx.x;
    for (int i = tid * 8; i < 16384; i += 2048)
        *(bf16x8*)(wo + i) = *(const bf16x8*)(Wout + i);
    __syncthreads();
    const int cl = tid & 15;                 // local column
    const int sl = tid >> 4;                 // K-slice 0..15
    const long c = (long)blockIdx.x * 16 + cl;
    float acc[16] = {};
    for (int dd = 0; dd < 64; ++dd) {
        const int d = sl * 64 + dd;
        const float x = ff_w2[(long)d * 2048 + c];
        #pragma unroll
        for (int j = 0; j < 16; ++j) acc[j] += x * (float)wo[j * 1024 + d];
    }
    #pragma unroll
    for (int j = 0; j < 16; ++j) red[sl][cl][j] = acc[j];
    __syncthreads();
    const int rj = tid & 15, rc = tid >> 4;  // rc 0..15
    float s = 0.f;
    #pragma unroll
    for (int sl2 = 0; sl2 < 16; ++sl2) s += red[sl2][rc][rj];
    Wof[(long)rj * 2048 + blockIdx.x * 16 + rc] = (bf16)s;
}

// ---------------- dot16m: MFMA skinny GEMM out[r][j] = X[r].Wo[j]  (K=1024) ----------------
__global__ __launch_bounds__(256) void lam_dot16m(const bf16* __restrict__ X,
                                                  const bf16* __restrict__ Wo,
                                                  float* __restrict__ out, int M) {
    __shared__ bf16 ws[16 * 1024];   // 32 KB, swizzled
    const int tid = threadIdx.x;
    for (int i = tid * 8; i < 16384; i += 2048) {
        const int col = i >> 10, k = i & 1023;
        *(bf16x8*)(ws + col * 1024 + (k ^ ((col & 7) << 3))) = *(const bf16x8*)(Wo + i);
    }
    __syncthreads();

    const int lane = tid & 63;
    const int wid  = tid >> 6;
    const long rbase = (long)blockIdx.x * 64 + wid * 16;
    if (rbase >= M) return;
    const int cidx = lane & 15;
    const int kg   = lane >> 4;

    const bf16* ar = X + (rbase + cidx) * 1024 + kg * 8;
    const int bbase = cidx * 1024;
    const int bxor  = (cidx & 7) << 3;

    f32x4 acc = {};
    #pragma unroll 4
    for (int kt = 0; kt < 32; ++kt) {
        bf16x8 a = *(const bf16x8*)(ar + kt * 32);
        bf16x8 b = *(const bf16x8*)(ws + bbase + ((kt * 32 + kg * 8) ^ bxor));
        acc = __builtin_amdgcn_mfma_f32_16x16x32_bf16(a, b, acc, 0, 0, 0);
    }
    #pragma unroll
    for (int q = 0; q < 4; ++q) {
        const long r = rbase + kg * 4 + q;
        if (r < M) out[r * 16 + cidx] = acc[q];
    }
}

// ---------------- LayerNorm helper (wave-wide, 16 vals/lane) ----------------
__device__ __forceinline__ void ln_row(float (&v)[16], const float* g, const float* bta,
                                       int lane, bf16* out) {
    float s = 0.f;
    #pragma unroll
    for (int e = 0; e < 16; ++e) s += v[e];
    #pragma unroll
    for (int m = 32; m >= 1; m >>= 1) s += __shfl_xor(s, m);
    const float mean = s * (1.0f / 1024.0f);
    float vs = 0.f;
    #pragma unroll
    for (int e = 0; e < 16; ++e) { float d = v[e] - mean; vs += d * d; }
    #pragma unroll
    for (int m = 32; m >= 1; m >>= 1) vs += __shfl_xor(vs, m);
    const float rstd = rsqrtf(vs * (1.0f / 1024.0f) + 1e-5f);
    const int kb = lane * 16;
    const float4* gp = (const float4*)(g + kb);
    const float4* bp = (const float4*)(bta + kb);
    float r[16];
    #pragma unroll
    for (int q = 0; q < 4; ++q) {
        float4 a = gp[q], c = bp[q];
        r[q*4+0] = (v[q*4+0] - mean) * rstd * a.x + c.x;
        r[q*4+1] = (v[q*4+1] - mean) * rstd * a.y + c.y;
        r[q*4+2] = (v[q*4+2] - mean) * rstd * a.z + c.z;
        r[q*4+3] = (v[q*4+3] - mean) * rstd * a.w + c.w;
    }
    bf16x8 o0, o1;
    #pragma unroll
    for (int e = 0; e < 8; ++e) { o0[e] = (bf16)r[e]; o1[e] = (bf16)r[8+e]; }
    bf16x8* yp = (bf16x8*)out;
    yp[0] = o0; yp[1] = o1;
}

// ---------------- LayerNorm: one wave per 1024-elem row (fp32 in) ----------------
__global__ __launch_bounds__(256) void lam_ln_f32(const float* __restrict__ X,
                                                  const float* __restrict__ g,
                                                  const float* __restrict__ bta,
                                                  bf16* __restrict__ Y) {
    const int lane = threadIdx.x & 63;
    const long row = (long)blockIdx.x * 4 + (threadIdx.x >> 6);
    const long base = row * 1024 + lane * 16;
    float v[16];
    const float4* p = (const float4*)(X + base);
    #pragma unroll
    for (int q = 0; q < 4; ++q) {
        float4 f = p[q];
        v[q*4+0]=f.x; v[q*4+1]=f.y; v[q*4+2]=f.z; v[q*4+3]=f.w;
    }
    ln_row(v, g, bta, lane, Y + base);
}

// ---------------- xtab/ltab/xt16: 68 distinct embedding rows + LN1 + Wout dots ----------------
__global__ __launch_bounds__(256) void lam_xtab(const float* __restrict__ tok,
                                                const float* __restrict__ pos,
                                                const float* __restrict__ g,
                                                const float* __restrict__ bta,
                                                const bf16* __restrict__ WoutB,
                                                float* __restrict__ xtab,
                                                bf16* __restrict__ ltab,
                                                float* __restrict__ xt16) {
    const int lane = threadIdx.x & 63;
    const int j = blockIdx.x * 4 + (threadIdx.x >> 6);
    if (j >= 68) return;
    const int t = j / 17, s = j % 17;
    float v[16];
    const float4* tp = (const float4*)(tok + (long)s * 1024 + lane * 16);
    const float4* pp = (const float4*)(pos + (long)t * 1024 + lane * 16);
    float4* xp = (float4*)(xtab + (long)j * 1024 + lane * 16);
    #pragma unroll
    for (int q = 0; q < 4; ++q) {
        float4 a = tp[q], c = pp[q];
        float4 o; o.x=a.x+c.x; o.y=a.y+c.y; o.z=a.z+c.z; o.w=a.w+c.w;
        xp[q] = o;
        v[q*4+0]=o.x; v[q*4+1]=o.y; v[q*4+2]=o.z; v[q*4+3]=o.w;
    }
    // xt16[j][jj] = x . Wout[jj]
    #pragma unroll
    for (int jj = 0; jj < 16; ++jj) {
        const bf16x8* wp = (const bf16x8*)(WoutB + (long)jj * 1024 + lane * 16);
        bf16x8 w0 = wp[0], w1 = wp[1];
        float d = 0.f;
        #pragma unroll
        for (int e = 0; e < 8; ++e) d += v[e]*(float)w0[e] + v[8+e]*(float)w1[e];
        #pragma unroll
        for (int m = 32; m >= 1; m >>= 1) d += __shfl_xor(d, m);
        if (lane == 0) xt16[j * 16 + jj] = d;
    }
    ln_row(v, g, bta, lane, ltab + (long)j * 1024 + lane * 16);
}

// ---------------- attention table: 4369 tuples x 8 heads, one wave each ----------------
__global__ __launch_bounds__(256) void lam_attn_tab(const bf16* __restrict__ qkvtab,
                                                    bf16* __restrict__ atab) {
    const int lane = threadIdx.x & 63;
    const int unit = blockIdx.x * 4 + (threadIdx.x >> 6);
    const int u = unit >> 3, h = unit & 7;
    int t, s1 = 0, s2 = 0, s3 = 0;
    if (u == 0) { t = 0; }
    else if (u < 17) { t = 1; s1 = u - 1; }
    else if (u < 273) { t = 2; int v = u - 17; s1 = v >> 4; s2 = v & 15; }
    else { t = 3; int v = u - 273; s1 = v >> 8; s2 = (v >> 4) & 15; s3 = v & 15; }
    const int qs = (t == 0) ? 16 : (t == 1 ? s1 : (t == 2 ? s2 : s3));
    const int qrow = t * 17 + qs;
    const int krow[4] = { 16, 17 + s1, 34 + s2, 51 + s3 };
    const int base = h * 128 + lane * 2;

    bf16x2 qu = *(const bf16x2*)(qkvtab + (long)qrow * 3072 + base);
    const float q0 = (float)qu[0], q1 = (float)qu[1];
    float sc[4], v0[4], v1[4];
    #pragma unroll
    for (int j = 0; j < 4; ++j) {
        if (j <= t) {
            const bf16* kp = qkvtab + (long)krow[j] * 3072 + 1024 + base;
            bf16x2 ku = *(const bf16x2*)(kp);
            bf16x2 vu = *(const bf16x2*)(kp + 1024);
            sc[j] = q0 * (float)ku[0] + q1 * (float)ku[1];
            v0[j] = (float)vu[0]; v1[j] = (float)vu[1];
        } else { sc[j] = 0.f; v0[j] = 0.f; v1[j] = 0.f; }
    }
    #pragma unroll
    for (int m = 1; m < 64; m <<= 1)
        #pragma unroll
        for (int j = 0; j < 4; ++j)
            sc[j] += __shfl_xor(sc[j], m);
    const float scale = 0.08838834764831845f;   // 1/sqrt(128)
    float mx = -1e30f;
    #pragma unroll
    for (int j = 0; j < 4; ++j) if (j <= t) mx = fmaxf(mx, sc[j] * scale);
    float sum = 0.f, a[4];
    #pragma unroll
    for (int j = 0; j < 4; ++j) if (j <= t) { a[j] = expf(sc[j] * scale - mx); sum += a[j]; }
    const float inv = 1.0f / sum;
    float o0 = 0.f, o1 = 0.f;
    #pragma unroll
    for (int j = 0; j < 4; ++j) if (j <= t) { o0 += a[j] * inv * v0[j]; o1 += a[j] * inv * v1[j]; }
    bf16x2 ov; ov[0] = (bf16)o0; ov[1] = (bf16)o1;
    *(bf16x2*)(atab + (long)u * 1024 + base) = ov;
}

// ---------------- gather + residual + LN3 (LN output only) ----------------
__global__ __launch_bounds__(256) void lam_gather_ln(const int* __restrict__ tg,
                                                     const float* __restrict__ xtab,
                                                     const bf16* __restrict__ aotab,
                                                     const bf16* __restrict__ caO,
                                                     const float* __restrict__ g,
                                                     const float* __restrict__ bta,
                                                     bf16* __restrict__ Y, long r0) {
    const int lane = threadIdx.x & 63;
    const long rl = (long)blockIdx.x * 4 + (threadIdx.x >> 6);
    const long r = r0 + rl;
    const long b = r >> 2;
    const int t = (int)(r & 3);
    const int tg0 = (t >= 1) ? tg[b*4] : 0;
    const int tg1 = (t >= 2) ? tg[b*4+1] : 0;
    const int tg2 = (t >= 3) ? tg[b*4+2] : 0;
    const int st = (t == 0) ? 16 : (t == 1 ? tg0 : (t == 2 ? tg1 : tg2));
    const long xrow = t * 17 + st;
    long idx;
    if (t == 0) idx = 0;
    else if (t == 1) idx = 1 + tg0;
    else if (t == 2) idx = 17 + tg0 * 16 + tg1;
    else idx = 273 + tg0 * 256 + tg1 * 16 + tg2;

    const int kb = lane * 16;
    float v[16];
    const float4* xp = (const float4*)(xtab + xrow * 1024 + kb);
    const bf16x8* ap = (const bf16x8*)(aotab + idx * 1024 + kb);
    const bf16x8* cp = (const bf16x8*)(caO + b * 1024 + kb);
    bf16x8 a0 = ap[0], a1 = ap[1], c0 = cp[0], c1 = cp[1];
    #pragma unroll
    for (int q = 0; q < 4; ++q) {
        float4 f = xp[q];
        v[q*4+0]=f.x; v[q*4+1]=f.y; v[q*4+2]=f.z; v[q*4+3]=f.w;
    }
    #pragma unroll
    for (int e = 0; e < 8; ++e) { v[e] += (float)a0[e] + (float)c0[e]; v[8+e] += (float)a1[e] + (float)c1[e]; }
    ln_row(v, g, bta, lane, Y + rl * 1024 + kb);
}

// ===================== GEMM epilogue (shared) =====================
template<int EPI, int IM>
__device__ __forceinline__ void gemm_epi(f32x4 (&acc)[IM][4], const float* bias,
                                         bf16* C, const bf16* R,
                                         long bm, long bn, int wrow, int wcol,
                                         int lane, int N) {
    const int lr = (lane >> 4) * 4;
    const int lc = lane & 15;
    #pragma unroll
    for (int i = 0; i < IM; ++i) {
        const long row0 = bm + wrow + i * 16 + lr;
        #pragma unroll
        for (int j = 0; j < 4; ++j) {
            const long col = bn + wcol + j * 16 + lc;
            const float bvs = bias[col];
            #pragma unroll
            for (int qq = 0; qq < 4; ++qq) {
                const long row = row0 + qq;
                float v = acc[i][j][qq] + bvs;
                const long idx = row * N + col;
                if (EPI == 1) v = 0.5f * v * (1.0f + erff(v * 0.70710678118654752f));
                if (EPI == 2) v = fmaxf(v, 0.0f);
                if (EPI == 3) v += (float)R[idx];
                C[idx] = (bf16)v;
            }
        }
    }
}

// ---------------- GEMM 2-phase (round-3/7 proven): TMx256, BK=64, 8 waves ----------------
template<int EPI, int TM>
__global__ __launch_bounds__(512, 2) void lam_gemm2(const bf16* __restrict__ A,
                                                    const bf16* __restrict__ W,
                                                    const float* __restrict__ bias,
                                                    bf16* C, const bf16* R,
                                                    int M, int N, int K) {
    constexpr int AR    = TM / 64;
    constexpr int ABYTE = TM * 128;
    constexpr int BUFB  = ABYTE + 32768;
    constexpr int IM    = TM / 32;
    __shared__ __attribute__((aligned(16))) char lds[2 * BUFB];

    const int t    = threadIdx.x;
    const int lane = t & 63;
    const int wid  = t >> 6;
    const int wm   = wid >> 2;
    const int wn   = wid & 3;

    const int gx   = gridDim.x;
    const int nwg  = gx * gridDim.y;
    const int orig = blockIdx.y * gx + blockIdx.x;
    const int q8 = nwg >> 3, r8 = nwg & 7;
    const int xcd = orig & 7, i8 = orig >> 3;
    const int wg  = (xcd < r8 ? xcd * (q8 + 1) : r8 * (q8 + 1) + (xcd - r8) * q8) + i8;
    const long bm = (long)(wg / gx) * TM;
    const long bn = (long)(wg % gx) * 256;

    const long rs = (long)K * 2;
    const char* Ag = (const char*)A + bm * rs;
    const char* Wg = (const char*)W + bn * rs;
    const int  srow = t >> 3;
    const int  scol = (((t & 7) ^ ((t >> 3) & 7)) << 4);
    const long g0   = (long)srow * rs + scol;

    const int xorq = (lane & 7) << 4;
    const int arow = wm * (TM / 2) + (lane & 15);
    const int brow = wn * 64 + (lane & 15);
    const int kq   = (lane >> 4) * 16;

    f32x4 acc[IM][4] = {};

    auto STAGE = [&](int buf, long kbyte) {
        char* base = lds + buf * BUFB + wid * 1024;
        const char* ga = Ag + g0 + kbyte;
        const char* gb = Wg + g0 + kbyte;
        #pragma unroll
        for (int r = 0; r < AR; ++r)
            gll16(ga + (long)r * 64 * rs, base + r * 8192);
        #pragma unroll
        for (int r = 0; r < 4; ++r)
            gll16(gb + (long)r * 64 * rs, base + ABYTE + r * 8192);
    };

    STAGE(0, 0);
    asm volatile("s_waitcnt vmcnt(0)" ::: "memory");
    __syncthreads();

    const int NT = K >> 6;
    int cur = 0;
    for (int kt = 0; kt < NT; ++kt) {
        if (kt + 1 < NT) STAGE(cur ^ 1, (long)(kt + 1) * 128);
        const char* ab = lds + cur * BUFB;
        const char* bb = ab + ABYTE;
        #pragma unroll
        for (int ks = 0; ks < 2; ++ks) {
            const int kc = kq + ks * 64;
            bf16x8 bvv[4];
            #pragma unroll
            for (int j = 0; j < 4; ++j) {
                const int x = (brow + j * 16) * 128 + kc;
                bvv[j] = *(const bf16x8*)(bb + (x ^ xorq));
            }
            #pragma unroll
            for (int i = 0; i < IM; ++i) {
                const int x = (arow + i * 16) * 128 + kc;
                bf16x8 avv = *(const bf16x8*)(ab + (x ^ xorq));
                #pragma unroll
                for (int j = 0; j < 4; ++j)
                    acc[i][j] = __builtin_amdgcn_mfma_f32_16x16x32_bf16(avv, bvv[j], acc[i][j], 0, 0, 0);
            }
        }
        asm volatile("s_waitcnt vmcnt(0)" ::: "memory");
        __syncthreads();
        cur ^= 1;
    }

    gemm_epi<EPI, IM>(acc, bias, C, R, bm, bn, wm * (TM / 2), wn * 64, lane, N);
}

static void gemm2(int epi, const bf16* A, const bf16* W, const float* bias, bf16* C,
                  const bf16* R, int M, int N, int K, hipStream_t s) {
    const long n256 = (long)(M >> 8) * (N >> 8);
    if (n256 >= 256 && (M & 255) == 0) {
        dim3 grid(N / 256, M / 256);
        switch (epi) {
            case 0: lam_gemm2<0,256><<<grid,512,0,s>>>(A,W,bias,C,R,M,N,K); break;
            case 1: lam_gemm2<1,256><<<grid,512,0,s>>>(A,W,bias,C,R,M,N,K); break;
            case 2: lam_gemm2<2,256><<<grid,512,0,s>>>(A,W,bias,C,R,M,N,K); break;
            default:lam_gemm2<3,256><<<grid,512,0,s>>>(A,W,bias,C,R,M,N,K); break;
        }
    } else {
        dim3 grid(N / 256, M / 128);
        switch (epi) {
            case 0: lam_gemm2<0,128><<<grid,512,0,s>>>(A,W,bias,C,R,M,N,K); break;
            case 1: lam_gemm2<1,128><<<grid,512,0,s>>>(A,W,bias,C,R,M,N,K); break;
            case 2: lam_gemm2<2,128><<<grid,512,0,s>>>(A,W,bias,C,R,M,N,K); break;
            default:lam_gemm2<3,128><<<grid,512,0,s>>>(A,W,bias,C,R,M,N,K); break;
        }
    }
}

// ---------------- fused FFN1 + logits: 256x256 tile, then contract with Wof ----------------
__global__ __launch_bounds__(512, 2) void lam_gemm_fl(const bf16* __restrict__ A,
                                                      const bf16* __restrict__ W,
                                                      const float* __restrict__ bias,
                                                      const bf16* __restrict__ Wof,
                                                      const int* __restrict__ tg,
                                                      const float* __restrict__ xt16,
                                                      const float* __restrict__ ao16,
                                                      const float* __restrict__ ca16,
                                                      const float* __restrict__ cb16,
                                                      float* __restrict__ out,
                                                      long r0, int K) {
    constexpr int ABYTE = 32768;            // A region: 256 rows x 64 k x 2B
    constexpr int BUFB  = 65536;
    __shared__ __attribute__((aligned(16))) char lds[2 * BUFB];

    const int t    = threadIdx.x;
    const int lane = t & 63;
    const int wid  = t >> 6;
    const int wm   = wid >> 2;
    const int wn   = wid & 3;

    const int gx   = gridDim.x;             // 8 (N/256)
    const int nwg  = gx * gridDim.y;
    const int orig = blockIdx.y * gx + blockIdx.x;
    const int q8 = nwg >> 3, r8 = nwg & 7;
    const int xcd = orig & 7, i8 = orig >> 3;
    const int wg  = (xcd < r8 ? xcd * (q8 + 1) : r8 * (q8 + 1) + (xcd - r8) * q8) + i8;
    const long bm = (long)(wg / gx) * 256;  // chunk-local row base
    const long bn = (long)(wg % gx) * 256;  // FFN column base

    const long rs = (long)K * 2;
    const char* Ag = (const char*)A + bm * rs;
    const char* Wg = (const char*)W + bn * rs;
    const int  srow = t >> 3;
    const int  scol = (((t & 7) ^ ((t >> 3) & 7)) << 4);
    const long g0   = (long)srow * rs + scol;

    const int xorq = (lane & 7) << 4;
    const int arow = wm * 128 + (lane & 15);
    const int brow = wn * 64 + (lane & 15);
    const int kq   = (lane >> 4) * 16;

    f32x4 acc[8][4] = {};

    auto STAGE = [&](int buf, long kbyte) {
        char* base = lds + buf * BUFB + wid * 1024;
        const char* ga = Ag + g0 + kbyte;
        const char* gb = Wg + g0 + kbyte;
        #pragma unroll
        for (int r = 0; r < 4; ++r)
            gll16(ga + (long)r * 64 * rs, base + r * 8192);
        #pragma unroll
        for (int r = 0; r < 4; ++r)
            gll16(gb + (long)r * 64 * rs, base + ABYTE + r * 8192);
    };

    STAGE(0, 0);
    asm volatile("s_waitcnt vmcnt(0)" ::: "memory");
    __syncthreads();

    const int NT = K >> 6;
    int cur = 0;
    for (int kt = 0; kt < NT; ++kt) {
        if (kt + 1 < NT) STAGE(cur ^ 1, (long)(kt + 1) * 128);
        const char* ab = lds + cur * BUFB;
        const char* bb = ab + ABYTE;
        #pragma unroll
        for (int ks = 0; ks < 2; ++ks) {
            const int kc = kq + ks * 64;
            bf16x8 bvv[4];
            #pragma unroll
            for (int j = 0; j < 4; ++j) {
                const int x = (brow + j * 16) * 128 + kc;
                bvv[j] = *(const bf16x8*)(bb + (x ^ xorq));
            }
            #pragma unroll
            for (int i = 0; i < 8; ++i) {
                const int x = (arow + i * 16) * 128 + kc;
                bf16x8 avv = *(const bf16x8*)(ab + (x ^ xorq));
                #pragma unroll
                for (int j = 0; j < 4; ++j)
                    acc[i][j] = __builtin_amdgcn_mfma_f32_16x16x32_bf16(avv, bvv[j], acc[i][j], 0, 0, 0);
            }
        }
        asm volatile("s_waitcnt vmcnt(0)" ::: "memory");
        __syncthreads();
        cur ^= 1;
    }

    // ---- write relu tile [256 rows][256 cols] bf16 into LDS, swizzled ----
    {
        const int lr = (lane >> 4) * 4;
        const int lc = lane & 15;
        #pragma unroll
        for (int i = 0; i < 8; ++i) {
            const int row0 = wm * 128 + i * 16 + lr;
            #pragma unroll
            for (int j = 0; j < 4; ++j) {
                const int col = wn * 64 + j * 16 + lc;
                const float bvs = bias[bn + col];
                #pragma unroll
                for (int qq = 0; qq < 4; ++qq) {
                    const int row = row0 + qq;
                    const float v = fmaxf(acc[i][j][qq] + bvs, 0.0f);
                    *(bf16*)(lds + row * 512 + ((col * 2) ^ ((row & 7) << 4))) = (bf16)v;
                }
            }
        }
    }
    __syncthreads();

    // ---- 2nd stage: out_partial[256][16] = tile @ WofT(slice bn..bn+255) ----
    const int cidx = lane & 15;
    const int kg   = lane >> 4;
    f32x4 acc2[2] = {};
    #pragma unroll
    for (int kt = 0; kt < 8; ++kt) {
        bf16x8 bfrag = *(const bf16x8*)(Wof + (long)cidx * 2048 + bn + kt * 32 + kg * 8);
        #pragma unroll
        for (int rt = 0; rt < 2; ++rt) {
            const int row = wid * 32 + rt * 16 + cidx;
            const int kby = (kt * 32 + kg * 8) * 2;
            bf16x8 afrag = *(const bf16x8*)(lds + row * 512 + (kby ^ ((row & 7) << 4)));
            acc2[rt] = __builtin_amdgcn_mfma_f32_16x16x32_bf16(afrag, bfrag, acc2[rt], 0, 0, 0);
        }
    }

    // ---- atomic accumulate (bn==0 block also adds tables) ----
    #pragma unroll
    for (int rt = 0; rt < 2; ++rt) {
        #pragma unroll
        for (int q = 0; q < 4; ++q) {
            const long rl = bm + wid * 32 + rt * 16 + kg * 4 + q;
            const long r = r0 + rl;
            float v = acc2[rt][q];
            if (bn == 0) {
                const long b = r >> 2;
                const int tt = (int)(r & 3);
                const int tg0 = (tt >= 1) ? tg[b*4] : 0;
                const int tg1 = (tt >= 2) ? tg[b*4+1] : 0;
                const int tg2 = (tt >= 3) ? tg[b*4+2] : 0;
                const int st = (tt == 0) ? 16 : (tt == 1 ? tg0 : (tt == 2 ? tg1 : tg2));
                const long xrow = tt * 17 + st;
                long idx;
                if (tt == 0) idx = 0;
                else if (tt == 1) idx = 1 + tg0;
                else if (tt == 2) idx = 17 + tg0 * 16 + tg1;
                else idx = 273 + tg0 * 256 + tg1 * 16 + tg2;
                v += xt16[xrow * 16 + cidx] + ao16[idx * 16 + cidx]
                   + ca16[b * 16 + cidx] + cb16[cidx];
            }
            atomicAdd(&out[r * 16 + cidx], v);
        }
    }
}

// =============================== host ===============================
extern "C" void kernel_launch(void* const* d_in, const int* in_sizes, int n_in,
                              void* d_out, int out_size, void* d_ws, size_t ws_size,
                              hipStream_t stream) {
    const float* context = (const float*)d_in[0];
    const int*   targets = (const int*)d_in[1];
    const float* tok_emb = (const float*)d_in[2];
    const float* pos_emb = (const float*)d_in[3];
    const float* cp_ln_g = (const float*)d_in[4];
    const float* cp_ln_b = (const float*)d_in[5];
    const float* cp_w    = (const float*)d_in[6];
    const float* cp_b    = (const float*)d_in[7];
    const float* sa_wq   = (const float*)d_in[8];
    const float* sa_bq   = (const float*)d_in[9];
    const float* sa_wk   = (const float*)d_in[10];
    const float* sa_bk   = (const float*)d_in[11];
    const float* sa_wv   = (const float*)d_in[12];
    const float* sa_bv   = (const float*)d_in[13];
    const float* sa_wo   = (const float*)d_in[14];
    const float* sa_bo   = (const float*)d_in[15];
    // ca_wq/bq (16,17), ca_wk/bk (18,19), ln2 (26,27): dead — kv len is 1
    const float* ca_wv   = (const float*)d_in[20];
    const float* ca_bv   = (const float*)d_in[21];
    const float* ca_wo   = (const float*)d_in[22];
    const float* ca_bo   = (const float*)d_in[23];
    const float* ln1_g   = (const float*)d_in[24];
    const float* ln1_b   = (const float*)d_in[25];
    const float* ln3_g   = (const float*)d_in[28];
    const float* ln3_b   = (const float*)d_in[29];
    const float* ff_w1   = (const float*)d_in[30];
    const float* ff_b1   = (const float*)d_in[31];
    const float* ff_w2   = (const float*)d_in[32];
    const float* ff_b2   = (const float*)d_in[33];
    const float* out_w   = (const float*)d_in[34];
    const float* out_b   = (const float*)d_in[35];

    char* ws = (char*)d_ws;
    size_t off = 0;
    auto take = [&](size_t bytes) -> char* {
        char* p = ws + off;
        off += (bytes + 255) & ~(size_t)255;
        return p;
    };
    // ---- persistent: bf16 weights + tables + caO + context scratch ----
    bf16*  Wcp   = (bf16*)take((size_t)1048576 * 2);
    bf16*  Wqkv  = (bf16*)take((size_t)3145728 * 2);
    bf16*  Wsao  = (bf16*)take((size_t)1048576 * 2);
    bf16*  Wcao  = (bf16*)take((size_t)1048576 * 2);
    bf16*  WvT   = (bf16*)take((size_t)1048576 * 2);
    bf16*  Wcomb = (bf16*)take((size_t)1048576 * 2);
    bf16*  Wff1  = (bf16*)take((size_t)2097152 * 2);
    bf16*  Wout  = (bf16*)take((size_t)16384 * 2);
    bf16*  Wof   = (bf16*)take((size_t)32768 * 2);
    float* bqkv  = (float*)take((size_t)3072 * 4);
    float* bcomb = (float*)take((size_t)1024 * 4);
    float* zb    = (float*)take((size_t)1024 * 4);
    float* cb16  = (float*)take((size_t)16 * 4);
    float* xtab  = (float*)take((size_t)128 * 1024 * 4);
    bf16*  ltab  = (bf16*)take((size_t)128 * 1024 * 2);
    bf16*  qkvtab= (bf16*)take((size_t)128 * 3072 * 2);
    bf16*  atab  = (bf16*)take((size_t)4608 * 1024 * 2);
    bf16*  aotab = (bf16*)take((size_t)4608 * 1024 * 2);
    bf16*  caO   = (bf16*)take((size_t)16384 * 1024 * 2);
    float* xt16  = (float*)take((size_t)128 * 16 * 4);
    float* ao16  = (float*)take((size_t)4608 * 16 * 4);
    float* ca16  = (float*)take((size_t)16384 * 16 * 4);
    bf16*  cbuf  = (bf16*)take((size_t)16384 * 1024 * 2);   // context scratch

    // ---- adaptive chunk pool: hb (rows*1024 bf16) only ----
    long chunk_rows = 65536;
    while (chunk_rows > 512 &&
           off + (size_t)chunk_rows * 2048 > ws_size)
        chunk_rows >>= 1;
    bf16* hb = (bf16*)take((size_t)chunk_rows * 1024 * 2);
    const long nchunks = 65536 / chunk_rows;

    // --- all weight fp32->bf16 conversions in ONE dispatch (ff_w2 stays fp32) ---
    {
        CvtJobs J;
        const float* srcs[8] = { cp_w, sa_wq, sa_wk, sa_wv, sa_wo, ca_wo, ff_w1, out_w };
        bf16* dsts[8] = { Wcp, Wqkv, Wqkv + 1048576, Wqkv + 2097152, Wsao, Wcao, Wff1, Wout };
        const int ns[8] = { 1048576, 1048576, 1048576, 1048576, 1048576, 1048576,
                            2097152, 16384 };
        int cum = 0;
        for (int j = 0; j < 8; ++j) {
            J.s[j] = srcs[j]; J.d[j] = dsts[j];
            J.blk[j] = cum; cum += ns[j] / 2048;
        }
        J.blk[8] = cum; J.blk[9] = cum;
        lam_cvt_all<<<cum, 256, 0, stream>>>(J);
    }
    // --- prep: packb + bcomb/zb + cb16 in ONE dispatch ---
    lam_prep<<<272, 256, 0, stream>>>(sa_bq, sa_bk, sa_bv, bqkv,
                                      ca_wo, ca_bv, ca_bo, bcomb, zb,
                                      Wout, ff_b2, out_b, cb16);

    // --- folds: Wcomb = ca_wo@ca_wv; Wof = Wout@ff_w2 ---
    lam_transpose<<<dim3(16, 16), 256, 0, stream>>>(ca_wv, WvT);
    gemm2(0, Wcao, WvT, zb, Wcomb, nullptr, 1024, 1024, 1024, stream);
    lam_wof2<<<128, 256, 0, stream>>>(Wout, ff_w2, Wof);

    // --- decoder tables: x/LN1/xt16 (68), QKV (68), attention (4369), O-proj, ao16 ---
    lam_xtab<<<17, 256, 0, stream>>>(tok_emb, pos_emb, ln1_g, ln1_b, Wout, xtab, ltab, xt16);
    gemm2(0, ltab, Wqkv, bqkv, qkvtab, nullptr, 128, 3072, 1024, stream);
    lam_attn_tab<<<8738, 256, 0, stream>>>(qkvtab, atab);
    gemm2(0, atab, Wsao, sa_bo, aotab, nullptr, 4608, 1024, 1024, stream);
    lam_dot16m<<<72, 256, 0, stream>>>(aotab, Wout, ao16, 4608);

    // --- context path (no memcpy): LN->caO(tmp); gelu-GEMM caO->cbuf; GEMM cbuf->caO ---
    lam_ln_f32<<<4096, 256, 0, stream>>>(context, cp_ln_g, cp_ln_b, caO);
    gemm2(1, caO, Wcp, cp_b, cbuf, nullptr, 16384, 1024, 1024, stream);
    gemm2(0, cbuf, Wcomb, bcomb, caO, nullptr, 16384, 1024, 1024, stream);
    lam_dot16m<<<256, 256, 0, stream>>>(caO, Wout, ca16, 16384);

    // --- decoder stream: zero out, then per chunk: gather+LN3 -> fused FFN1+logits ---
    hipMemsetAsync(d_out, 0, (size_t)65536 * 16 * 4, stream);
    for (long c = 0; c < nchunks; ++c) {
        const long r0 = c * chunk_rows;
        lam_gather_ln<<<chunk_rows / 4, 256, 0, stream>>>(targets, xtab, aotab, caO,
                                                          ln3_g, ln3_b, hb, r0);
        lam_gemm_fl<<<dim3(8, chunk_rows / 256), 512, 0, stream>>>(
            hb, Wff1, ff_b1, Wof, targets, xt16, ao16, ca16, cb16,
            (float*)d_out, r0, 1024);
    }

    (void)in_sizes; (void)n_in; (void)out_size;
}